// Round 4
// baseline (988.280 us; speedup 1.0000x reference)
//
#include <hip/hip_runtime.h>

// HeteroSAGE on MI355X — round 7: persistent pipelined GEMM + raw barrier.
// R6 post-mortem: occupancy 2.5x -> null. Diagnosis: __syncthreads() on
// gfx950 emits s_waitcnt vmcnt(0) before s_barrier — every version drained
// ALL outstanding vmem at each block's barrier, so no steady-state load
// queue ever forms (explains ~1 TB/s invariant to occupancy/structure).
// Fix: mfma_gemm_pipe = persistent blocks (768, 3/CU), grid-stride tiles,
// next-tile A prefetch kept in flight ACROSS a raw s_barrier (only
// lgkmcnt(0) for the LDS transpose), counted-vmcnt epilogue waits.
// Encoders (f32) + dual-pass card/merch updates keep the R3 kernel.

#define N_TX    200000
#define N_CARD  50000
#define N_MERCH 10000
#define NE      200000

typedef __attribute__((ext_vector_type(8))) short short8;
typedef __attribute__((ext_vector_type(4))) float f32x4;

__device__ inline unsigned short f2b(float f) {
    unsigned u = __builtin_bit_cast(unsigned, f);
    unsigned r = (u + 0x7fffu + ((u >> 16) & 1u)) >> 16;   // RNE
    return (unsigned short)r;
}
__device__ inline float b2f(unsigned short s) {
    return __builtin_bit_cast(float, (unsigned)s << 16);
}

// ---------------------------------------------------------------------------
// Persistent pipelined GEMM: OUT[M,128] = act(A@W + bias + P1[I1]+P2[I2]),
// optional head reduction. A is bf16 [M][128], K=128 fixed. WT bf16 [128][128]
// pre-transposed. One 16-row m-tile per wave, 64-row tiles, grid-stride.
// Raw barrier (no vmcnt drain) keeps next-tile A loads + gathers in flight.
__global__ __launch_bounds__(256, 3) void mfma_gemm_pipe(
    const unsigned short* __restrict__ A, const unsigned short* __restrict__ WT,
    const float* __restrict__ bias,
    const unsigned short* __restrict__ P1, const int* __restrict__ I1,
    const unsigned short* __restrict__ P2, const int* __restrict__ I2,
    int do_relu, const float* __restrict__ h2W, const float* __restrict__ h2b,
    void* __restrict__ OUT, int M)
{
    __shared__ unsigned short Ts[2][64 * 136];
    const int tid  = threadIdx.x;
    const int wave = tid >> 6;
    const int lane = tid & 63;
    const int quad = lane >> 4;
    const int l15  = lane & 15;
    const int rgrp = tid >> 4;                 // 0..15: epilogue row-group
    const int c0   = l15 * 8;                  // epilogue column block
    const int nT   = (M + 63) >> 6;
    const int step = gridDim.x;

    float bias8[8], h2w8[8];
#pragma unroll
    for (int j = 0; j < 8; ++j) {
        bias8[j] = bias ? bias[c0 + j] : 0.f;
        h2w8[j]  = h2W  ? h2W[c0 + j]  : 0.f;
    }

    unsigned short* OUTb = (unsigned short*)OUT;
    float* OUTf = (float*)OUT;

    short8 afC[4], afN[4];
    auto loadA = [&](short8* dst, int t) {
        int r = t * 64 + wave * 16 + l15;
        int rc = (r < M) ? r : 0;
        const unsigned short* ap = A + (size_t)rc * 128 + quad * 8;
#pragma unroll
        for (int kk = 0; kk < 4; ++kk)
            dst[kk] = *reinterpret_cast<const short8*>(ap + kk * 32);
    };

    const int t0 = blockIdx.x;
    if (t0 < nT) loadA(afC, t0);

    int buf = 0;
    for (int t = t0; t < nT; t += step, buf ^= 1) {
        // epilogue row indices for this tile (cheap, L2)
        int idx1[4], idx2[4];
#pragma unroll
        for (int p = 0; p < 4; ++p) {
            int r = t * 64 + p * 16 + rgrp;
            int rc = (r < M) ? r : 0;
            idx1[p] = I1 ? I1[rc] : 0;
            idx2[p] = I2 ? I2[rc] : 0;
        }

        // MFMA on resident A fragments; B from L1-hot WT (32KB, reused/block)
        f32x4 acc[8];
#pragma unroll
        for (int nt = 0; nt < 8; ++nt) acc[nt] = (f32x4){0.f, 0.f, 0.f, 0.f};
#pragma unroll
        for (int nt = 0; nt < 8; ++nt) {
            const unsigned short* bp = WT + (nt * 16 + l15) * 128 + quad * 8;
#pragma unroll
            for (int kk = 0; kk < 4; ++kk) {
                short8 bf = *reinterpret_cast<const short8*>(bp + kk * 32);
                acc[nt] = __builtin_amdgcn_mfma_f32_16x16x32_bf16(
                    afC[kk], bf, acc[nt], 0, 0, 0);
            }
        }

        // P-row gathers for this tile (hide under LDS transpose + barrier)
        short8 p1v[4], p2v[4];
        if (P1) {
#pragma unroll
            for (int p = 0; p < 4; ++p)
                p1v[p] = *reinterpret_cast<const short8*>(
                    P1 + (size_t)idx1[p] * 128 + c0);
        }
        if (P2) {
#pragma unroll
            for (int p = 0; p < 4; ++p)
                p2v[p] = *reinterpret_cast<const short8*>(
                    P2 + (size_t)idx2[p] * 128 + c0);
        }

        // next tile's A prefetch — issued AFTER gathers so the epilogue's
        // gather-wait (counted vmcnt) leaves these in flight
        const int tn = t + step;
        if (tn < nT) loadA(afN, tn);

        // transpose acc -> LDS (bf16, stride 136)
        unsigned short* ts = &Ts[buf][0];
        {
            int lrow0 = wave * 16 + quad * 4;
#pragma unroll
            for (int nt = 0; nt < 8; ++nt) {
                int col = nt * 16 + l15;
#pragma unroll
                for (int reg = 0; reg < 4; ++reg)
                    ts[(lrow0 + reg) * 136 + col] = f2b(acc[nt][reg]);
            }
        }

        // raw barrier: wait ONLY on LDS writes; vmem (afN, gathers) stays live
        __builtin_amdgcn_sched_barrier(0);
        asm volatile("s_waitcnt lgkmcnt(0)" ::: "memory");
        __builtin_amdgcn_s_barrier();
        __builtin_amdgcn_sched_barrier(0);

        // epilogue: row-major re-read, add bias/P, relu, coalesced store
#pragma unroll
        for (int p = 0; p < 4; ++p) {
            const int rloc = p * 16 + rgrp;
            const int r = t * 64 + rloc;
            const bool valid = r < M;
            short8 av = *reinterpret_cast<const short8*>(&ts[rloc * 136 + c0]);
            float hsum = 0.f;
            short8 ov;
#pragma unroll
            for (int j = 0; j < 8; ++j) {
                float o = b2f((unsigned short)av[j]) + bias8[j];
                if (P1) o += b2f((unsigned short)p1v[p][j]);
                if (P2) o += b2f((unsigned short)p2v[p][j]);
                if (do_relu) o = fmaxf(o, 0.f);
                if (h2W) hsum += o * h2w8[j];
                else ov[j] = (short)f2b(o);
            }
            if (h2W) {
                hsum += __shfl_xor(hsum, 1);
                hsum += __shfl_xor(hsum, 2);
                hsum += __shfl_xor(hsum, 4);
                hsum += __shfl_xor(hsum, 8);
                if (l15 == 0 && valid) OUTf[r] = hsum + h2b[0];
            } else if (valid) {
                *reinterpret_cast<short8*>(OUTb + (size_t)r * 128 + c0) = ov;
            }
        }

        // rotate prefetched A into place (waits afN via counted vmcnt;
        // stores remain outstanding)
#pragma unroll
        for (int kk = 0; kk < 4; ++kk) afC[kk] = afN[kk];
    }
}

// ---------------------------------------------------------------------------
// Basic GEMM (R3 structure, control group): f32-A encoders and dual-pass
// card/merch updates. Block: 64 rows x 128 cols; 4 waves.
__global__ __launch_bounds__(256, 4) void mfma_gemm(
    const void* __restrict__ A1, int a1_f32, const int* __restrict__ rowIdx1,
    int K1, const unsigned short* __restrict__ WT1,
    const void* __restrict__ A2, int K2, const unsigned short* __restrict__ WT2,
    const float* __restrict__ bias,
    int do_relu, void* __restrict__ OUT, int M)
{
    __shared__ unsigned short Ts[64 * 136];
    const int tid  = threadIdx.x;
    const int wave = tid >> 6;
    const int lane = tid & 63;
    const int quad = lane >> 4;
    const int l15  = lane & 15;
    const int base = blockIdx.x * 64;
    const int rgrp = tid >> 4;
    const int c0   = l15 * 8;

    f32x4 acc[8];
#pragma unroll
    for (int nt = 0; nt < 8; ++nt)
        acc[nt] = (f32x4){0.f, 0.f, 0.f, 0.f};

    for (int pass = 0; pass < 2; ++pass) {
        const void* A = (pass == 0) ? A1 : A2;
        if (!A) break;
        const int K = (pass == 0) ? K1 : K2;
        const unsigned short* WTg = (pass == 0) ? WT1 : WT2;
        const int* rIdx = (pass == 0) ? rowIdx1 : nullptr;
        const int a_f32 = (pass == 0) ? a1_f32 : 0;
        const int nkk = K >> 5;

        short8 af[4];
        {
            int r = base + wave * 16 + l15;
            int rc = (r < M) ? r : 0;
            int ar = rIdx ? rIdx[rc] : rc;
            if (a_f32) {
                const float* ap = (const float*)A + (size_t)ar * K + quad * 8;
#pragma unroll
                for (int kk = 0; kk < 4; ++kk) if (kk < nkk) {
                    float4 u = *reinterpret_cast<const float4*>(ap + kk * 32);
                    float4 v = *reinterpret_cast<const float4*>(ap + kk * 32 + 4);
                    short8 t;
                    t[0] = (short)f2b(u.x); t[1] = (short)f2b(u.y);
                    t[2] = (short)f2b(u.z); t[3] = (short)f2b(u.w);
                    t[4] = (short)f2b(v.x); t[5] = (short)f2b(v.y);
                    t[6] = (short)f2b(v.z); t[7] = (short)f2b(v.w);
                    af[kk] = t;
                }
            } else {
                const unsigned short* ap =
                    (const unsigned short*)A + (size_t)ar * K + quad * 8;
#pragma unroll
                for (int kk = 0; kk < 4; ++kk) if (kk < nkk)
                    af[kk] = *reinterpret_cast<const short8*>(ap + kk * 32);
            }
        }

#pragma unroll
        for (int nt = 0; nt < 8; ++nt) {
            short8 bf[4];
            const unsigned short* bp = WTg + (nt * 16 + l15) * K + quad * 8;
#pragma unroll
            for (int kk = 0; kk < 4; ++kk) if (kk < nkk)
                bf[kk] = *reinterpret_cast<const short8*>(bp + kk * 32);
#pragma unroll
            for (int kk = 0; kk < 4; ++kk) if (kk < nkk)
                acc[nt] = __builtin_amdgcn_mfma_f32_16x16x32_bf16(
                    af[kk], bf[kk], acc[nt], 0, 0, 0);
        }
    }

#pragma unroll
    for (int nt = 0; nt < 8; ++nt) {
        int col = nt * 16 + l15;
        int lrow0 = wave * 16 + quad * 4;
#pragma unroll
        for (int reg = 0; reg < 4; ++reg)
            Ts[(lrow0 + reg) * 136 + col] = f2b(acc[nt][reg]);
    }

    float bias8[8];
#pragma unroll
    for (int j = 0; j < 8; ++j)
        bias8[j] = bias ? bias[c0 + j] : 0.f;

    __syncthreads();

    unsigned short* OUTb = (unsigned short*)OUT;
#pragma unroll
    for (int p = 0; p < 4; ++p) {
        const int rloc = p * 16 + rgrp;
        const int r = base + rloc;
        if (r >= M) continue;
        short8 av = *reinterpret_cast<const short8*>(&Ts[rloc * 136 + c0]);
        short8 ov;
#pragma unroll
        for (int j = 0; j < 8; ++j) {
            float o = b2f((unsigned short)av[j]) + bias8[j];
            if (do_relu) o = fmaxf(o, 0.f);
            ov[j] = (short)f2b(o);
        }
        *reinterpret_cast<short8*>(OUTb + (size_t)r * 128 + c0) = ov;
    }
}

// ---------------------------------------------------------------------------
// Weight prep: fp32 [K][128] -> bf16 transposed [128][K]; job 6/13 also does
// Wsum=Wr0+Wr2 and bsum=bl0+bl2. 18 jobs x 16384-short slots.
__global__ __launch_bounds__(256) void convert_weights(
    const float* __restrict__ tx_W, const float* __restrict__ card_proj_W,
    const float* __restrict__ merch_proj_W, const float* __restrict__ h1_W,
    const float* __restrict__ conv_Wl, const float* __restrict__ conv_Wr,
    const float* __restrict__ conv_bl,
    unsigned short* __restrict__ WT, float* __restrict__ bsum)
{
    int job = blockIdx.y;
    int K = 128;
    const float* src = nullptr;
    const float* src2 = nullptr;
    if (job == 0) src = tx_W;
    else if (job == 1) { src = card_proj_W; K = 64; }
    else if (job == 2) { src = merch_proj_W; K = 64; }
    else if (job == 3) src = h1_W;
    else {
        int l = (job - 4) / 7, e = (job - 4) % 7;
        const float* Wl = conv_Wl + (size_t)l * 4 * 16384;
        const float* Wr = conv_Wr + (size_t)l * 4 * 16384;
        switch (e) {
            case 0: src = Wl; break;
            case 1: src = Wl + 16384; break;
            case 2: src = Wl + 2 * 16384; break;
            case 3: src = Wl + 3 * 16384; break;
            case 4: src = Wr + 16384; break;
            case 5: src = Wr + 3 * 16384; break;
            default:
                src = Wr; src2 = Wr + 2 * 16384;
                if (blockIdx.x == 0 && threadIdx.x < 128) {
                    const float* bl = conv_bl + (size_t)l * 4 * 128;
                    bsum[l * 128 + threadIdx.x] =
                        bl[threadIdx.x] + bl[2 * 128 + threadIdx.x];
                }
                break;
        }
    }
    int e = blockIdx.x * 256 + threadIdx.x;
    if (e < (K << 7)) {
        int n = (K == 128) ? (e >> 7) : (e >> 6);
        int k = e & (K - 1);
        float v = src[(size_t)k * 128 + n];
        if (src2) v += src2[(size_t)k * 128 + n];
        WT[(size_t)job * 16384 + n * K + k] = f2b(v);
    }
}

// ---------------------------------------------------------------------------
// CSR build (edges fixed within call; reused across layers)
__global__ __launch_bounds__(256) void hist_kernel(
    const int* __restrict__ e_card, const int* __restrict__ e_merch,
    int* __restrict__ hist_c, int* __restrict__ hist_m, int E)
{
    int i = blockIdx.x * 256 + threadIdx.x;
    if (i < E) {
        atomicAdd(&hist_c[e_card[i]], 1);
        atomicAdd(&hist_m[e_merch[i]], 1);
    }
}

// 2 blocks: block 0 scans card hist, block 1 scans merch hist
__global__ __launch_bounds__(1024) void scan2_kernel(
    const int* __restrict__ hist_c, int* __restrict__ offs_c, int* __restrict__ cur_c, int nc,
    const int* __restrict__ hist_m, int* __restrict__ offs_m, int* __restrict__ cur_m, int nm)
{
    const int* hist = (blockIdx.x == 0) ? hist_c : hist_m;
    int* offs = (blockIdx.x == 0) ? offs_c : offs_m;
    int* cursor = (blockIdx.x == 0) ? cur_c : cur_m;
    int n = (blockIdx.x == 0) ? nc : nm;
    __shared__ int wsum[16];
    __shared__ int s_carry;
    const int tid = threadIdx.x, lane = tid & 63, wid = tid >> 6;
    if (tid == 0) s_carry = 0;
    __syncthreads();
    for (int base = 0; base < n; base += 1024) {
        int i = base + tid;
        int v = (i < n) ? hist[i] : 0;
        int x = v;
#pragma unroll
        for (int d = 1; d < 64; d <<= 1) {
            int t = __shfl_up(x, d);
            if (lane >= d) x += t;
        }
        if (lane == 63) wsum[wid] = x;
        __syncthreads();
        if (wid == 0) {
            int y = (lane < 16) ? wsum[lane] : 0;
#pragma unroll
            for (int d = 1; d < 16; d <<= 1) {
                int t = __shfl_up(y, d);
                if (lane >= d) y += t;
            }
            if (lane < 16) wsum[lane] = y;
        }
        __syncthreads();
        int wbase = (wid > 0) ? wsum[wid - 1] : 0;
        int excl = s_carry + wbase + x - v;
        if (i < n) { offs[i] = excl; cursor[i] = excl; }
        __syncthreads();
        if (tid == 0) s_carry += wsum[15];
        __syncthreads();
    }
    if (threadIdx.x == 0) offs[n] = s_carry;
}

__global__ __launch_bounds__(256) void place_kernel(
    const int* __restrict__ e_card, const int* __restrict__ e_tx_c,
    const int* __restrict__ e_merch, const int* __restrict__ e_tx_m,
    int* __restrict__ cur_c, int* __restrict__ eidx_c,
    int* __restrict__ cur_m, int* __restrict__ eidx_m, int E)
{
    int i = blockIdx.x * 256 + threadIdx.x;
    if (i < E) {
        int pc = atomicAdd(&cur_c[e_card[i]], 1);
        eidx_c[pc] = e_tx_c[i];
        int pm = atomicAdd(&cur_m[e_merch[i]], 1);
        eidx_m[pm] = e_tx_m[i];
    }
}

// one wave per dst node; quad-per-edge (4 edges in flight), 16 lanes x 16B
// per gathered row (256B coalesced), cross-quad shuffle reduce.
__global__ __launch_bounds__(256) void gather_mean(
    const unsigned short* __restrict__ h_src, const int* __restrict__ offs,
    const int* __restrict__ eidx, unsigned short* __restrict__ out_mean, int n_dst)
{
    const int lane = threadIdx.x & 63;
    const int l15 = lane & 15;
    const int quad = lane >> 4;
    const int d = blockIdx.x * 4 + (threadIdx.x >> 6);
    if (d >= n_dst) return;
    const int s = offs[d], e = offs[d + 1];
    float a[8] = {0.f, 0.f, 0.f, 0.f, 0.f, 0.f, 0.f, 0.f};
    for (int p = s + quad; p < e; p += 4) {
        int tx = eidx[p];
        short8 v = *reinterpret_cast<const short8*>(
            h_src + (size_t)tx * 128 + l15 * 8);
#pragma unroll
        for (int j = 0; j < 8; ++j) a[j] += b2f((unsigned short)v[j]);
    }
#pragma unroll
    for (int j = 0; j < 8; ++j) {
        a[j] += __shfl_xor(a[j], 16);
        a[j] += __shfl_xor(a[j], 32);
    }
    if (quad == 0) {
        const float inv = (e > s) ? 1.0f / (float)(e - s) : 0.f;
        short8 o;
#pragma unroll
        for (int j = 0; j < 8; ++j) o[j] = (short)f2b(a[j] * inv);
        *reinterpret_cast<short8*>(out_mean + (size_t)d * 128 + l15 * 8) = o;
    }
}

// ---------------------------------------------------------------------------
extern "C" void kernel_launch(void* const* d_in, const int* in_sizes, int n_in,
                              void* d_out, int out_size, void* d_ws, size_t ws_size,
                              hipStream_t stream)
{
    const float* tx_x        = (const float*)d_in[0];
    const int*   card_ids    = (const int*)d_in[1];
    const int*   merch_ids   = (const int*)d_in[2];
    const int*   e_card      = (const int*)d_in[3];
    const int*   e_tx_c      = (const int*)d_in[4];
    const int*   e_merch     = (const int*)d_in[5];
    const int*   e_tx_m      = (const int*)d_in[6];
    const float* card_emb    = (const float*)d_in[7];
    const float* merch_emb   = (const float*)d_in[8];
    const float* card_proj_W = (const float*)d_in[9];
    const float* card_proj_b = (const float*)d_in[10];
    const float* merch_proj_W= (const float*)d_in[11];
    const float* merch_proj_b= (const float*)d_in[12];
    const float* tx_W        = (const float*)d_in[13];
    const float* tx_b        = (const float*)d_in[14];
    const float* conv_Wl     = (const float*)d_in[15];
    const float* conv_bl     = (const float*)d_in[16];
    const float* conv_Wr     = (const float*)d_in[17];
    const float* h1_W        = (const float*)d_in[18];
    const float* h1_b        = (const float*)d_in[19];
    const float* h2_W        = (const float*)d_in[20];
    const float* h2_b        = (const float*)d_in[21];

    char* wsb = (char*)d_ws;
    auto alloc = [&](size_t bytes) {
        char* p = wsb; wsb += (bytes + 255) & ~(size_t)255; return p;
    };
    unsigned short* h_tx       = (unsigned short*)alloc((size_t)N_TX * 128 * 2);
    unsigned short* h_card     = (unsigned short*)alloc((size_t)N_CARD * 128 * 2);
    unsigned short* h_merch    = (unsigned short*)alloc((size_t)N_MERCH * 128 * 2);
    unsigned short* p_card     = (unsigned short*)alloc((size_t)N_CARD * 128 * 2);
    unsigned short* p_merch    = (unsigned short*)alloc((size_t)N_MERCH * 128 * 2);
    unsigned short* mean_card  = (unsigned short*)alloc((size_t)N_CARD * 128 * 2);
    unsigned short* mean_merch = (unsigned short*)alloc((size_t)N_MERCH * 128 * 2);
    unsigned short* WT         = (unsigned short*)alloc((size_t)18 * 16384 * 2);
    float* bsum = (float*)alloc(2 * 128 * 4);
    int* hist_c = (int*)alloc((size_t)(N_CARD + N_MERCH) * 4);  // one memset
    int* hist_m = hist_c + N_CARD;
    int* offs_c = (int*)alloc((size_t)(N_CARD + 1) * 4);
    int* cur_c  = (int*)alloc((size_t)N_CARD * 4);
    int* eidx_c = (int*)alloc((size_t)NE * 4);
    int* offs_m = (int*)alloc((size_t)(N_MERCH + 1) * 4);
    int* cur_m  = (int*)alloc((size_t)N_MERCH * 4);
    int* eidx_m = (int*)alloc((size_t)NE * 4);

    auto WTj = [&](int job) { return WT + (size_t)job * 16384; };

    auto gemm_basic = [&](const void* A1, int a1f32, const int* ri, int K1,
                          const unsigned short* W1, const void* A2, int K2,
                          const unsigned short* W2, const float* bias,
                          int relu, void* out, int M) {
        mfma_gemm<<<dim3((M + 63) / 64), dim3(256), 0, stream>>>(
            A1, a1f32, ri, K1, W1, A2, K2, W2, bias, relu, out, M);
    };
    auto gemm_pipe = [&](const unsigned short* A, const unsigned short* W,
                         const float* bias, const unsigned short* P1,
                         const int* I1, const unsigned short* P2, const int* I2,
                         int relu, const float* h2w, const float* h2bb,
                         void* out, int M) {
        int nT = (M + 63) / 64;
        int grid = nT < 768 ? nT : 768;
        mfma_gemm_pipe<<<dim3(grid), dim3(256), 0, stream>>>(
            A, W, bias, P1, I1, P2, I2, relu, h2w, h2bb, out, M);
    };

    // weight prep + CSR build
    convert_weights<<<dim3(64, 18), dim3(256), 0, stream>>>(
        tx_W, card_proj_W, merch_proj_W, h1_W, conv_Wl, conv_Wr, conv_bl,
        WT, bsum);
    hipMemsetAsync(hist_c, 0, (size_t)(N_CARD + N_MERCH) * 4, stream);
    hist_kernel<<<dim3((NE + 255) / 256), dim3(256), 0, stream>>>(
        e_card, e_merch, hist_c, hist_m, NE);
    scan2_kernel<<<dim3(2), dim3(1024), 0, stream>>>(
        hist_c, offs_c, cur_c, N_CARD, hist_m, offs_m, cur_m, N_MERCH);
    place_kernel<<<dim3((NE + 255) / 256), dim3(256), 0, stream>>>(
        e_card, e_tx_c, e_merch, e_tx_m, cur_c, eidx_c, cur_m, eidx_m, NE);

    // input encoders (fp32 A converted inline)
    gemm_basic(tx_x, 1, nullptr, 128, WTj(0), nullptr, 0, nullptr, tx_b,
               1, h_tx, N_TX);
    gemm_basic(card_emb, 1, card_ids, 64, WTj(1), nullptr, 0, nullptr,
               card_proj_b, 0, h_card, N_CARD);
    gemm_basic(merch_emb, 1, merch_ids, 64, WTj(2), nullptr, 0, nullptr,
               merch_proj_b, 0, h_merch, N_MERCH);

    for (int l = 0; l < 2; ++l) {
        const float* bl = conv_bl + (size_t)l * 4 * 128;
        int j = 4 + l * 7;   // Wl0,Wl1,Wl2,Wl3,Wr1,Wr3,Wsum

        gather_mean<<<dim3((N_CARD + 3) / 4), dim3(256), 0, stream>>>(
            h_tx, offs_c, eidx_c, mean_card, N_CARD);
        gather_mean<<<dim3((N_MERCH + 3) / 4), dim3(256), 0, stream>>>(
            h_tx, offs_m, eidx_m, mean_merch, N_MERCH);

        // p_* = h_* @ Wl[0/2] (pre-update hidden), for the tx-side gather
        gemm_pipe(h_card, WTj(j + 0), nullptr, nullptr, nullptr,
                  nullptr, nullptr, 0, nullptr, nullptr, p_card, N_CARD);
        gemm_pipe(h_merch, WTj(j + 2), nullptr, nullptr, nullptr,
                  nullptr, nullptr, 0, nullptr, nullptr, p_merch, N_MERCH);

        // card/merch updates: relu(mean@Wl + h@Wr + bl)  (in-place, row-local)
        gemm_basic(mean_card, 0, nullptr, 128, WTj(j + 1), h_card, 128,
                   WTj(j + 4), bl + 1 * 128, 1, h_card, N_CARD);
        gemm_basic(mean_merch, 0, nullptr, 128, WTj(j + 3), h_merch, 128,
                   WTj(j + 5), bl + 3 * 128, 1, h_merch, N_MERCH);

        // tx update: relu(h_tx@(Wr0+Wr2) + bl0+bl2 + p_card[e_card] + p_merch[e_merch])
        gemm_pipe(h_tx, WTj(j + 6), bsum + l * 128, p_card, e_card,
                  p_merch, e_merch, 1, nullptr, nullptr, h_tx, N_TX);
    }

    // head: logits = relu(h_tx @ h1_W + h1_b) @ h2_W + h2_b  (fp32 out)
    gemm_pipe(h_tx, WTj(3), h1_b, nullptr, nullptr, nullptr, nullptr,
              1, h2_W, h2_b, d_out, N_TX);
}

// Round 5
// 700.745 us; speedup vs baseline: 1.4103x; 1.4103x over previous
//
#include <hip/hip_runtime.h>

// HeteroSAGE on MI355X — round 8: fusion + dead-code elimination.
// R7 post-mortem: persistent/pipelined GEMM regressed (988us). Four
// structural rewrites all land at ~104us per M=200k dispatch = traffic/1TB/s.
// Accept the empirical law (per-dispatch time ~ traffic at ~1 TB/s) and
// shrink the numerator:
//  - fused2 mode A: tx encoder + layer1 tx-update in one pass (h_tx0 rows
//    stay in LDS as stage-2 A-operand). Writes h_tx0 (for gathers) + h_tx1.
//  - fused2 mode B: layer2 tx-update + head. h_tx2 never touches HBM:
//    stage2 output reduced against h2_W in C-layout, writes 0.8MB logits.
//  - layer2 card/merch updates + their gather_means are DEAD (h_card2/
//    h_merch2 never consumed) — dropped (4 dispatches, ~120MB traffic).
// Big-GEMM traffic: 400MB/4 dispatches -> ~250MB/2 dispatches.

#define N_TX    200000
#define N_CARD  50000
#define N_MERCH 10000
#define NE      200000

typedef __attribute__((ext_vector_type(8))) short short8;
typedef __attribute__((ext_vector_type(4))) float f32x4;

__device__ inline unsigned short f2b(float f) {
    unsigned u = __builtin_bit_cast(unsigned, f);
    unsigned r = (u + 0x7fffu + ((u >> 16) & 1u)) >> 16;   // RNE
    return (unsigned short)r;
}
__device__ inline float b2f(unsigned short s) {
    return __builtin_bit_cast(float, (unsigned)s << 16);
}

// ---------------------------------------------------------------------------
// Fused two-GEMM kernel. 64-row tiles, 4 waves, one 16-row m-tile per wave.
// mode A (OUT0 != null):  h0 = relu(A@W1 + b1)        -> store OUT0 (bf16)
//                         out = relu(h0@W2 + b2 + P1[I1]+P2[I2]) -> OUT1 bf16
// mode B (OUT0 == null):  h  = relu(A@W1 + b1 + P1[I1]+P2[I2])   (LDS only)
//                         out[r] = relu(h@W2 + b2) . h2w + h2b   -> OUT1 f32
// A: f32 (a_f32=1) or bf16, [M][128]. W1T/W2T bf16 [128][128] pre-transposed.
__global__ __launch_bounds__(256, 3) void fused2(
    const void* __restrict__ A, int a_f32,
    const unsigned short* __restrict__ W1T, const float* __restrict__ b1,
    const unsigned short* __restrict__ W2T, const float* __restrict__ b2,
    const unsigned short* __restrict__ P1, const int* __restrict__ I1,
    const unsigned short* __restrict__ P2, const int* __restrict__ I2,
    unsigned short* __restrict__ OUT0,
    const float* __restrict__ h2w, const float* __restrict__ h2b,
    void* __restrict__ OUT1, int M)
{
    __shared__ float Tf[64 * 132];            // fp32 transpose tile
    __shared__ unsigned short Tb[64 * 136];   // bf16 stage-2 A tile
    const int tid  = threadIdx.x;
    const int wave = tid >> 6;
    const int lane = tid & 63;
    const int quad = lane >> 4;
    const int l15  = lane & 15;
    const int base = blockIdx.x * 64;
    const int rgrp = tid >> 4;                // 0..15: row-pass row group
    const int c0   = l15 * 8;                 // row-pass column block
    const bool modeA = (OUT0 != nullptr);

    // prologue: row-pass gather indices (latency hidden by stage 1)
    int idx1[4], idx2[4];
#pragma unroll
    for (int p = 0; p < 4; ++p) {
        int r = base + p * 16 + rgrp;
        int rc = (r < M) ? r : 0;
        idx1[p] = I1 ? I1[rc] : 0;
        idx2[p] = I2 ? I2[rc] : 0;
    }

    // ---- stage 1: A-frags from global
    short8 af[4];
    {
        int r = base + wave * 16 + l15;
        int rc = (r < M) ? r : 0;
        if (a_f32) {
            const float* ap = (const float*)A + (size_t)rc * 128 + quad * 8;
#pragma unroll
            for (int kk = 0; kk < 4; ++kk) {
                float4 u = *reinterpret_cast<const float4*>(ap + kk * 32);
                float4 v = *reinterpret_cast<const float4*>(ap + kk * 32 + 4);
                short8 t;
                t[0] = (short)f2b(u.x); t[1] = (short)f2b(u.y);
                t[2] = (short)f2b(u.z); t[3] = (short)f2b(u.w);
                t[4] = (short)f2b(v.x); t[5] = (short)f2b(v.y);
                t[6] = (short)f2b(v.z); t[7] = (short)f2b(v.w);
                af[kk] = t;
            }
        } else {
            const unsigned short* ap =
                (const unsigned short*)A + (size_t)rc * 128 + quad * 8;
#pragma unroll
            for (int kk = 0; kk < 4; ++kk)
                af[kk] = *reinterpret_cast<const short8*>(ap + kk * 32);
        }
    }

    f32x4 acc[8];
#pragma unroll
    for (int nt = 0; nt < 8; ++nt) acc[nt] = (f32x4){0.f, 0.f, 0.f, 0.f};
#pragma unroll
    for (int nt = 0; nt < 8; ++nt) {
        const unsigned short* bp = W1T + (nt * 16 + l15) * 128 + quad * 8;
#pragma unroll
        for (int kk = 0; kk < 4; ++kk) {
            short8 bf = *reinterpret_cast<const short8*>(bp + kk * 32);
            acc[nt] = __builtin_amdgcn_mfma_f32_16x16x32_bf16(
                af[kk], bf, acc[nt], 0, 0, 0);
        }
    }

    // P-row gathers (only depend on idx; hide under transpose + barrier)
    short8 p1v[4], p2v[4];
    if (P1) {
#pragma unroll
        for (int p = 0; p < 4; ++p)
            p1v[p] = *reinterpret_cast<const short8*>(
                P1 + (size_t)idx1[p] * 128 + c0);
    }
    if (P2) {
#pragma unroll
        for (int p = 0; p < 4; ++p)
            p2v[p] = *reinterpret_cast<const short8*>(
                P2 + (size_t)idx2[p] * 128 + c0);
    }

    // ---- transpose stage-1 result
    const int lrow0 = wave * 16 + quad * 4;
    if (modeA) {
        // h0 = relu(acc + b1) -> bf16 tile (this IS h_tx0)
#pragma unroll
        for (int nt = 0; nt < 8; ++nt) {
            float bb = b1 ? b1[nt * 16 + l15] : 0.f;
#pragma unroll
            for (int reg = 0; reg < 4; ++reg)
                Tb[(lrow0 + reg) * 136 + nt * 16 + l15] =
                    f2b(fmaxf(acc[nt][reg] + bb, 0.f));
        }
    } else {
        // raw fp32 z -> Tf (bias/P/relu applied in row-pass)
#pragma unroll
        for (int nt = 0; nt < 8; ++nt)
#pragma unroll
            for (int reg = 0; reg < 4; ++reg)
                Tf[(lrow0 + reg) * 132 + nt * 16 + l15] = acc[nt][reg];
    }
    __syncthreads();

    if (modeA) {
        // store h0 rows (coalesced 16B per lane)
#pragma unroll
        for (int p = 0; p < 4; ++p) {
            const int rloc = p * 16 + rgrp;
            const int r = base + rloc;
            if (r < M) {
                short8 hv = *reinterpret_cast<const short8*>(&Tb[rloc * 136 + c0]);
                *reinterpret_cast<short8*>(OUT0 + (size_t)r * 128 + c0) = hv;
            }
        }
    } else {
        // row-pass 1: h = relu(z + b1 + P1 + P2) -> bf16 tile
        float b1r[8];
#pragma unroll
        for (int j = 0; j < 8; ++j) b1r[j] = b1 ? b1[c0 + j] : 0.f;
#pragma unroll
        for (int p = 0; p < 4; ++p) {
            const int rloc = p * 16 + rgrp;
            float4 u = *reinterpret_cast<const float4*>(&Tf[rloc * 132 + c0]);
            float4 v = *reinterpret_cast<const float4*>(&Tf[rloc * 132 + c0 + 4]);
            float o[8] = {u.x, u.y, u.z, u.w, v.x, v.y, v.z, v.w};
            short8 ov;
#pragma unroll
            for (int j = 0; j < 8; ++j) {
                float t = o[j] + b1r[j];
                if (P1) t += b2f((unsigned short)p1v[p][j]);
                if (P2) t += b2f((unsigned short)p2v[p][j]);
                ov[j] = (short)f2b(fmaxf(t, 0.f));
            }
            *reinterpret_cast<short8*>(&Tb[rloc * 136 + c0]) = ov;
        }
        __syncthreads();
    }

    // ---- stage 2: A-frags from the bf16 tile
    short8 af2[4];
#pragma unroll
    for (int kk = 0; kk < 4; ++kk)
        af2[kk] = *reinterpret_cast<const short8*>(
            &Tb[(wave * 16 + l15) * 136 + quad * 8 + kk * 32]);

    f32x4 acc2[8];
#pragma unroll
    for (int nt = 0; nt < 8; ++nt) acc2[nt] = (f32x4){0.f, 0.f, 0.f, 0.f};
#pragma unroll
    for (int nt = 0; nt < 8; ++nt) {
        const unsigned short* bp = W2T + (nt * 16 + l15) * 128 + quad * 8;
#pragma unroll
        for (int kk = 0; kk < 4; ++kk) {
            short8 bf = *reinterpret_cast<const short8*>(bp + kk * 32);
            acc2[nt] = __builtin_amdgcn_mfma_f32_16x16x32_bf16(
                af2[kk], bf, acc2[nt], 0, 0, 0);
        }
    }

    if (!modeA) {
        // head in C-layout: o = relu(acc2 + b2); logit = o . h2w + h2b
        float hsum[4] = {0.f, 0.f, 0.f, 0.f};
#pragma unroll
        for (int nt = 0; nt < 8; ++nt) {
            float bb = b2 ? b2[nt * 16 + l15] : 0.f;
            float w = h2w[nt * 16 + l15];
#pragma unroll
            for (int reg = 0; reg < 4; ++reg) {
                float o = fmaxf(acc2[nt][reg] + bb, 0.f);
                hsum[reg] += o * w;
            }
        }
        float* OUTf = (float*)OUT1;
#pragma unroll
        for (int reg = 0; reg < 4; ++reg) {
            float h = hsum[reg];
            h += __shfl_xor(h, 1);
            h += __shfl_xor(h, 2);
            h += __shfl_xor(h, 4);
            h += __shfl_xor(h, 8);
            int r = base + wave * 16 + quad * 4 + reg;
            if (l15 == 0 && r < M) OUTf[r] = h + h2b[0];
        }
    } else {
        // transpose stage-2, then row-pass 2: +b2+P, relu -> OUT1 bf16
#pragma unroll
        for (int nt = 0; nt < 8; ++nt)
#pragma unroll
            for (int reg = 0; reg < 4; ++reg)
                Tf[(lrow0 + reg) * 132 + nt * 16 + l15] = acc2[nt][reg];
        __syncthreads();
        float b2r[8];
#pragma unroll
        for (int j = 0; j < 8; ++j) b2r[j] = b2 ? b2[c0 + j] : 0.f;
        unsigned short* OB = (unsigned short*)OUT1;
#pragma unroll
        for (int p = 0; p < 4; ++p) {
            const int rloc = p * 16 + rgrp;
            const int r = base + rloc;
            float4 u = *reinterpret_cast<const float4*>(&Tf[rloc * 132 + c0]);
            float4 v = *reinterpret_cast<const float4*>(&Tf[rloc * 132 + c0 + 4]);
            float o[8] = {u.x, u.y, u.z, u.w, v.x, v.y, v.z, v.w};
            short8 ov;
#pragma unroll
            for (int j = 0; j < 8; ++j) {
                float t = o[j] + b2r[j];
                if (P1) t += b2f((unsigned short)p1v[p][j]);
                if (P2) t += b2f((unsigned short)p2v[p][j]);
                ov[j] = (short)f2b(fmaxf(t, 0.f));
            }
            if (r < M)
                *reinterpret_cast<short8*>(OB + (size_t)r * 128 + c0) = ov;
        }
    }
}

// ---------------------------------------------------------------------------
// Basic GEMM (R3/R6 structure): encoders (f32 A, optional rowIdx) and
// dual-input card/merch updates, p-GEMMs. Block: 64 rows x 128 cols; 4 waves.
__global__ __launch_bounds__(256, 4) void mfma_gemm(
    const void* __restrict__ A1, int a1_f32, const int* __restrict__ rowIdx1,
    int K1, const unsigned short* __restrict__ WT1,
    const void* __restrict__ A2, int K2, const unsigned short* __restrict__ WT2,
    const float* __restrict__ bias,
    int do_relu, void* __restrict__ OUT, int M)
{
    __shared__ unsigned short Ts[64 * 136];
    const int tid  = threadIdx.x;
    const int wave = tid >> 6;
    const int lane = tid & 63;
    const int quad = lane >> 4;
    const int l15  = lane & 15;
    const int base = blockIdx.x * 64;
    const int rgrp = tid >> 4;
    const int c0   = l15 * 8;

    f32x4 acc[8];
#pragma unroll
    for (int nt = 0; nt < 8; ++nt)
        acc[nt] = (f32x4){0.f, 0.f, 0.f, 0.f};

    for (int pass = 0; pass < 2; ++pass) {
        const void* A = (pass == 0) ? A1 : A2;
        if (!A) break;
        const int K = (pass == 0) ? K1 : K2;
        const unsigned short* WTg = (pass == 0) ? WT1 : WT2;
        const int* rIdx = (pass == 0) ? rowIdx1 : nullptr;
        const int a_f32 = (pass == 0) ? a1_f32 : 0;
        const int nkk = K >> 5;

        short8 af[4];
        {
            int r = base + wave * 16 + l15;
            int rc = (r < M) ? r : 0;
            int ar = rIdx ? rIdx[rc] : rc;
            if (a_f32) {
                const float* ap = (const float*)A + (size_t)ar * K + quad * 8;
#pragma unroll
                for (int kk = 0; kk < 4; ++kk) if (kk < nkk) {
                    float4 u = *reinterpret_cast<const float4*>(ap + kk * 32);
                    float4 v = *reinterpret_cast<const float4*>(ap + kk * 32 + 4);
                    short8 t;
                    t[0] = (short)f2b(u.x); t[1] = (short)f2b(u.y);
                    t[2] = (short)f2b(u.z); t[3] = (short)f2b(u.w);
                    t[4] = (short)f2b(v.x); t[5] = (short)f2b(v.y);
                    t[6] = (short)f2b(v.z); t[7] = (short)f2b(v.w);
                    af[kk] = t;
                }
            } else {
                const unsigned short* ap =
                    (const unsigned short*)A + (size_t)ar * K + quad * 8;
#pragma unroll
                for (int kk = 0; kk < 4; ++kk) if (kk < nkk)
                    af[kk] = *reinterpret_cast<const short8*>(ap + kk * 32);
            }
        }

#pragma unroll
        for (int nt = 0; nt < 8; ++nt) {
            short8 bf[4];
            const unsigned short* bp = WTg + (nt * 16 + l15) * K + quad * 8;
#pragma unroll
            for (int kk = 0; kk < 4; ++kk) if (kk < nkk)
                bf[kk] = *reinterpret_cast<const short8*>(bp + kk * 32);
#pragma unroll
            for (int kk = 0; kk < 4; ++kk) if (kk < nkk)
                acc[nt] = __builtin_amdgcn_mfma_f32_16x16x32_bf16(
                    af[kk], bf[kk], acc[nt], 0, 0, 0);
        }
    }

#pragma unroll
    for (int nt = 0; nt < 8; ++nt) {
        int col = nt * 16 + l15;
        int lrow0 = wave * 16 + quad * 4;
#pragma unroll
        for (int reg = 0; reg < 4; ++reg)
            Ts[(lrow0 + reg) * 136 + col] = f2b(acc[nt][reg]);
    }

    float bias8[8];
#pragma unroll
    for (int j = 0; j < 8; ++j)
        bias8[j] = bias ? bias[c0 + j] : 0.f;

    __syncthreads();

    unsigned short* OUTb = (unsigned short*)OUT;
#pragma unroll
    for (int p = 0; p < 4; ++p) {
        const int rloc = p * 16 + rgrp;
        const int r = base + rloc;
        if (r >= M) continue;
        short8 av = *reinterpret_cast<const short8*>(&Ts[rloc * 136 + c0]);
        short8 ov;
#pragma unroll
        for (int j = 0; j < 8; ++j) {
            float o = b2f((unsigned short)av[j]) + bias8[j];
            if (do_relu) o = fmaxf(o, 0.f);
            ov[j] = (short)f2b(o);
        }
        *reinterpret_cast<short8*>(OUTb + (size_t)r * 128 + c0) = ov;
    }
}

// ---------------------------------------------------------------------------
// Weight prep: fp32 [K][128] -> bf16 transposed [128][K]; job 6/13 also does
// Wsum=Wr0+Wr2 and bsum=bl0+bl2. 18 jobs x 16384-short slots.
__global__ __launch_bounds__(256) void convert_weights(
    const float* __restrict__ tx_W, const float* __restrict__ card_proj_W,
    const float* __restrict__ merch_proj_W, const float* __restrict__ h1_W,
    const float* __restrict__ conv_Wl, const float* __restrict__ conv_Wr,
    const float* __restrict__ conv_bl,
    unsigned short* __restrict__ WT, float* __restrict__ bsum)
{
    int job = blockIdx.y;
    int K = 128;
    const float* src = nullptr;
    const float* src2 = nullptr;
    if (job == 0) src = tx_W;
    else if (job == 1) { src = card_proj_W; K = 64; }
    else if (job == 2) { src = merch_proj_W; K = 64; }
    else if (job == 3) src = h1_W;
    else {
        int l = (job - 4) / 7, e = (job - 4) % 7;
        const float* Wl = conv_Wl + (size_t)l * 4 * 16384;
        const float* Wr = conv_Wr + (size_t)l * 4 * 16384;
        switch (e) {
            case 0: src = Wl; break;
            case 1: src = Wl + 16384; break;
            case 2: src = Wl + 2 * 16384; break;
            case 3: src = Wl + 3 * 16384; break;
            case 4: src = Wr + 16384; break;
            case 5: src = Wr + 3 * 16384; break;
            default:
                src = Wr; src2 = Wr + 2 * 16384;
                if (blockIdx.x == 0 && threadIdx.x < 128) {
                    const float* bl = conv_bl + (size_t)l * 4 * 128;
                    bsum[l * 128 + threadIdx.x] =
                        bl[threadIdx.x] + bl[2 * 128 + threadIdx.x];
                }
                break;
        }
    }
    int e = blockIdx.x * 256 + threadIdx.x;
    if (e < (K << 7)) {
        int n = (K == 128) ? (e >> 7) : (e >> 6);
        int k = e & (K - 1);
        float v = src[(size_t)k * 128 + n];
        if (src2) v += src2[(size_t)k * 128 + n];
        WT[(size_t)job * 16384 + n * K + k] = f2b(v);
    }
}

// ---------------------------------------------------------------------------
// CSR build (edges fixed within call; reused across layers)
__global__ __launch_bounds__(256) void hist_kernel(
    const int* __restrict__ e_card, const int* __restrict__ e_merch,
    int* __restrict__ hist_c, int* __restrict__ hist_m, int E)
{
    int i = blockIdx.x * 256 + threadIdx.x;
    if (i < E) {
        atomicAdd(&hist_c[e_card[i]], 1);
        atomicAdd(&hist_m[e_merch[i]], 1);
    }
}

// 2 blocks: block 0 scans card hist, block 1 scans merch hist
__global__ __launch_bounds__(1024) void scan2_kernel(
    const int* __restrict__ hist_c, int* __restrict__ offs_c, int* __restrict__ cur_c, int nc,
    const int* __restrict__ hist_m, int* __restrict__ offs_m, int* __restrict__ cur_m, int nm)
{
    const int* hist = (blockIdx.x == 0) ? hist_c : hist_m;
    int* offs = (blockIdx.x == 0) ? offs_c : offs_m;
    int* cursor = (blockIdx.x == 0) ? cur_c : cur_m;
    int n = (blockIdx.x == 0) ? nc : nm;
    __shared__ int wsum[16];
    __shared__ int s_carry;
    const int tid = threadIdx.x, lane = tid & 63, wid = tid >> 6;
    if (tid == 0) s_carry = 0;
    __syncthreads();
    for (int base = 0; base < n; base += 1024) {
        int i = base + tid;
        int v = (i < n) ? hist[i] : 0;
        int x = v;
#pragma unroll
        for (int d = 1; d < 64; d <<= 1) {
            int t = __shfl_up(x, d);
            if (lane >= d) x += t;
        }
        if (lane == 63) wsum[wid] = x;
        __syncthreads();
        if (wid == 0) {
            int y = (lane < 16) ? wsum[lane] : 0;
#pragma unroll
            for (int d = 1; d < 16; d <<= 1) {
                int t = __shfl_up(y, d);
                if (lane >= d) y += t;
            }
            if (lane < 16) wsum[lane] = y;
        }
        __syncthreads();
        int wbase = (wid > 0) ? wsum[wid - 1] : 0;
        int excl = s_carry + wbase + x - v;
        if (i < n) { offs[i] = excl; cursor[i] = excl; }
        __syncthreads();
        if (tid == 0) s_carry += wsum[15];
        __syncthreads();
    }
    if (threadIdx.x == 0) offs[n] = s_carry;
}

__global__ __launch_bounds__(256) void place_kernel(
    const int* __restrict__ e_card, const int* __restrict__ e_tx_c,
    const int* __restrict__ e_merch, const int* __restrict__ e_tx_m,
    int* __restrict__ cur_c, int* __restrict__ eidx_c,
    int* __restrict__ cur_m, int* __restrict__ eidx_m, int E)
{
    int i = blockIdx.x * 256 + threadIdx.x;
    if (i < E) {
        int pc = atomicAdd(&cur_c[e_card[i]], 1);
        eidx_c[pc] = e_tx_c[i];
        int pm = atomicAdd(&cur_m[e_merch[i]], 1);
        eidx_m[pm] = e_tx_m[i];
    }
}

// one wave per dst node; quad-per-edge (4 edges in flight), 16 lanes x 16B
// per gathered row (256B coalesced), cross-quad shuffle reduce.
__global__ __launch_bounds__(256) void gather_mean(
    const unsigned short* __restrict__ h_src, const int* __restrict__ offs,
    const int* __restrict__ eidx, unsigned short* __restrict__ out_mean, int n_dst)
{
    const int lane = threadIdx.x & 63;
    const int l15 = lane & 15;
    const int quad = lane >> 4;
    const int d = blockIdx.x * 4 + (threadIdx.x >> 6);
    if (d >= n_dst) return;
    const int s = offs[d], e = offs[d + 1];
    float a[8] = {0.f, 0.f, 0.f, 0.f, 0.f, 0.f, 0.f, 0.f};
    for (int p = s + quad; p < e; p += 4) {
        int tx = eidx[p];
        short8 v = *reinterpret_cast<const short8*>(
            h_src + (size_t)tx * 128 + l15 * 8);
#pragma unroll
        for (int j = 0; j < 8; ++j) a[j] += b2f((unsigned short)v[j]);
    }
#pragma unroll
    for (int j = 0; j < 8; ++j) {
        a[j] += __shfl_xor(a[j], 16);
        a[j] += __shfl_xor(a[j], 32);
    }
    if (quad == 0) {
        const float inv = (e > s) ? 1.0f / (float)(e - s) : 0.f;
        short8 o;
#pragma unroll
        for (int j = 0; j < 8; ++j) o[j] = (short)f2b(a[j] * inv);
        *reinterpret_cast<short8*>(out_mean + (size_t)d * 128 + l15 * 8) = o;
    }
}

// ---------------------------------------------------------------------------
extern "C" void kernel_launch(void* const* d_in, const int* in_sizes, int n_in,
                              void* d_out, int out_size, void* d_ws, size_t ws_size,
                              hipStream_t stream)
{
    const float* tx_x        = (const float*)d_in[0];
    const int*   card_ids    = (const int*)d_in[1];
    const int*   merch_ids   = (const int*)d_in[2];
    const int*   e_card      = (const int*)d_in[3];
    const int*   e_tx_c      = (const int*)d_in[4];
    const int*   e_merch     = (const int*)d_in[5];
    const int*   e_tx_m      = (const int*)d_in[6];
    const float* card_emb    = (const float*)d_in[7];
    const float* merch_emb   = (const float*)d_in[8];
    const float* card_proj_W = (const float*)d_in[9];
    const float* card_proj_b = (const float*)d_in[10];
    const float* merch_proj_W= (const float*)d_in[11];
    const float* merch_proj_b= (const float*)d_in[12];
    const float* tx_W        = (const float*)d_in[13];
    const float* tx_b        = (const float*)d_in[14];
    const float* conv_Wl     = (const float*)d_in[15];
    const float* conv_bl     = (const float*)d_in[16];
    const float* conv_Wr     = (const float*)d_in[17];
    const float* h1_W        = (const float*)d_in[18];
    const float* h1_b        = (const float*)d_in[19];
    const float* h2_W        = (const float*)d_in[20];
    const float* h2_b        = (const float*)d_in[21];

    char* wsb = (char*)d_ws;
    auto alloc = [&](size_t bytes) {
        char* p = wsb; wsb += (bytes + 255) & ~(size_t)255; return p;
    };
    unsigned short* h_tx0      = (unsigned short*)alloc((size_t)N_TX * 128 * 2);
    unsigned short* h_tx1      = (unsigned short*)alloc((size_t)N_TX * 128 * 2);
    unsigned short* h_card     = (unsigned short*)alloc((size_t)N_CARD * 128 * 2);
    unsigned short* h_merch    = (unsigned short*)alloc((size_t)N_MERCH * 128 * 2);
    unsigned short* p_card     = (unsigned short*)alloc((size_t)N_CARD * 128 * 2);
    unsigned short* p_merch    = (unsigned short*)alloc((size_t)N_MERCH * 128 * 2);
    unsigned short* mean_card  = (unsigned short*)alloc((size_t)N_CARD * 128 * 2);
    unsigned short* mean_merch = (unsigned short*)alloc((size_t)N_MERCH * 128 * 2);
    unsigned short* WT         = (unsigned short*)alloc((size_t)18 * 16384 * 2);
    float* bsum = (float*)alloc(2 * 128 * 4);
    int* hist_c = (int*)alloc((size_t)(N_CARD + N_MERCH) * 4);  // one memset
    int* hist_m = hist_c + N_CARD;
    int* offs_c = (int*)alloc((size_t)(N_CARD + 1) * 4);
    int* cur_c  = (int*)alloc((size_t)N_CARD * 4);
    int* eidx_c = (int*)alloc((size_t)NE * 4);
    int* offs_m = (int*)alloc((size_t)(N_MERCH + 1) * 4);
    int* cur_m  = (int*)alloc((size_t)N_MERCH * 4);
    int* eidx_m = (int*)alloc((size_t)NE * 4);

    auto WTj = [&](int job) { return WT + (size_t)job * 16384; };

    auto gemm_basic = [&](const void* A1, int a1f32, const int* ri, int K1,
                          const unsigned short* W1, const void* A2, int K2,
                          const unsigned short* W2, const float* bias,
                          int relu, void* out, int M) {
        mfma_gemm<<<dim3((M + 63) / 64), dim3(256), 0, stream>>>(
            A1, a1f32, ri, K1, W1, A2, K2, W2, bias, relu, out, M);
    };

    // weight prep + CSR build
    convert_weights<<<dim3(64, 18), dim3(256), 0, stream>>>(
        tx_W, card_proj_W, merch_proj_W, h1_W, conv_Wl, conv_Wr, conv_bl,
        WT, bsum);
    hipMemsetAsync(hist_c, 0, (size_t)(N_CARD + N_MERCH) * 4, stream);
    hist_kernel<<<dim3((NE + 255) / 256), dim3(256), 0, stream>>>(
        e_card, e_merch, hist_c, hist_m, NE);
    scan2_kernel<<<dim3(2), dim3(1024), 0, stream>>>(
        hist_c, offs_c, cur_c, N_CARD, hist_m, offs_m, cur_m, N_MERCH);
    place_kernel<<<dim3((NE + 255) / 256), dim3(256), 0, stream>>>(
        e_card, e_tx_c, e_merch, e_tx_m, cur_c, eidx_c, cur_m, eidx_m, NE);

    // card/merch encoders (fp32 A, gathered by ids)
    gemm_basic(card_emb, 1, card_ids, 64, WTj(1), nullptr, 0, nullptr,
               card_proj_b, 0, h_card, N_CARD);
    gemm_basic(merch_emb, 1, merch_ids, 64, WTj(2), nullptr, 0, nullptr,
               merch_proj_b, 0, h_merch, N_MERCH);

    // layer-1 p projections (need h_card0/h_merch0 only)
    gemm_basic(h_card, 0, nullptr, 128, WTj(4), nullptr, 0, nullptr, nullptr,
               0, p_card, N_CARD);
    gemm_basic(h_merch, 0, nullptr, 128, WTj(6), nullptr, 0, nullptr, nullptr,
               0, p_merch, N_MERCH);

    // FUSED-A: tx encoder + layer-1 tx update
    // h_tx0 = relu(tx_x@txW + txb); h_tx1 = relu(h_tx0@Wsum1 + bsum1 + p_c + p_m)
    fused2<<<dim3((N_TX + 63) / 64), dim3(256), 0, stream>>>(
        tx_x, 1, WTj(0), tx_b, WTj(10), bsum,
        p_card, e_card, p_merch, e_merch,
        h_tx0, nullptr, nullptr, h_tx1, N_TX);

    // layer-1 card/merch aggregation + updates (read h_tx0)
    gather_mean<<<dim3((N_CARD + 3) / 4), dim3(256), 0, stream>>>(
        h_tx0, offs_c, eidx_c, mean_card, N_CARD);
    gather_mean<<<dim3((N_MERCH + 3) / 4), dim3(256), 0, stream>>>(
        h_tx0, offs_m, eidx_m, mean_merch, N_MERCH);
    gemm_basic(mean_card, 0, nullptr, 128, WTj(5), h_card, 128, WTj(8),
               conv_bl + 128, 1, h_card, N_CARD);
    gemm_basic(mean_merch, 0, nullptr, 128, WTj(7), h_merch, 128, WTj(9),
               conv_bl + 3 * 128, 1, h_merch, N_MERCH);

    // layer-2 p projections (h_card1/h_merch1)
    gemm_basic(h_card, 0, nullptr, 128, WTj(11), nullptr, 0, nullptr, nullptr,
               0, p_card, N_CARD);
    gemm_basic(h_merch, 0, nullptr, 128, WTj(13), nullptr, 0, nullptr, nullptr,
               0, p_merch, N_MERCH);

    // (layer-2 card/merch updates + their gather_means are dead code: h_card2/
    //  h_merch2 are never consumed — skipped.)

    // FUSED-B: layer-2 tx update + head. h_tx2 never hits HBM.
    // logits = relu(relu(h_tx1@Wsum2 + bsum2 + p_c + p_m)@h1W + h1b).h2W + h2b
    fused2<<<dim3((N_TX + 63) / 64), dim3(256), 0, stream>>>(
        h_tx1, 0, WTj(17), bsum + 128, WTj(3), h1_b,
        p_card, e_card, p_merch, e_merch,
        nullptr, h2_W, h2_b, d_out, N_TX);
}